// Round 1
// baseline (189.786 us; speedup 1.0000x reference)
//
#include <hip/hip_runtime.h>
#include <math.h>

#define NE 8
#define DD 1024
#define HH 2048
#define NTOK 1024
#define NSLOT 2048

typedef short short8v __attribute__((ext_vector_type(8)));
typedef float f32x4 __attribute__((ext_vector_type(4)));

static __device__ __forceinline__ unsigned short f2bf(float f) {
  unsigned int x = __float_as_uint(f);
  return (unsigned short)((x + 0x7fffu + ((x >> 16) & 1u)) >> 16);
}

// ---------------------------------------------------------------------------
// Transpose + f32->bf16 convert: in f32 [R][C] per expert -> out bf16 [C][R]
// per expert. Output rows are granule-swizzled: within each 128B block of an
// output row r, the logical 16B granule g is stored at position g ^ (r&7).
// This makes later linear LDS staging produce a bank-conflict-free layout.
// ---------------------------------------------------------------------------
__global__ __launch_bounds__(256) void ktranspose(const float* __restrict__ in,
                                                  unsigned short* __restrict__ out,
                                                  int R, int C) {
  __shared__ unsigned short tl[64][72];  // padded to de-conflict column reads
  int e = blockIdx.z;
  int r0 = blockIdx.y * 64;
  int c0 = blockIdx.x * 64;
  const float* ein = in + (size_t)e * R * C;
  char* eout = (char*)(out + (size_t)e * C * R);
  int tid = threadIdx.x;
#pragma unroll
  for (int p = 0; p < 4; ++p) {
    int row = p * 16 + (tid >> 4);
    int c4 = (tid & 15) * 4;
    float4 v = *(const float4*)(ein + (size_t)(r0 + row) * C + c0 + c4);
    tl[row][c4 + 0] = f2bf(v.x);
    tl[row][c4 + 1] = f2bf(v.y);
    tl[row][c4 + 2] = f2bf(v.z);
    tl[row][c4 + 3] = f2bf(v.w);
  }
  __syncthreads();
#pragma unroll
  for (int q = 0; q < 2; ++q) {
    int c = q * 32 + (tid >> 3);
    int seg = tid & 7;  // logical granule: covers r = seg*8 .. seg*8+7
    short8v ov;
#pragma unroll
    for (int j = 0; j < 8; ++j) ov[j] = (short)tl[seg * 8 + j][c];
    int cg = c0 + c;
    int s = seg ^ (cg & 7);
    *(short8v*)(eout + (size_t)cg * (R * 2) + (size_t)r0 * 2 + (s << 4)) = ov;
  }
}

// ---------------------------------------------------------------------------
// Router: one wave per token. Exact f32 dot products, softmax over 8, top-2.
// slot s (flat k*N+n): e_sel[s], w_sel[s].
// ---------------------------------------------------------------------------
__global__ __launch_bounds__(64) void krouter(const float* __restrict__ x,
                                              const float* __restrict__ gw,
                                              int* __restrict__ e_sel,
                                              float* __restrict__ w_sel) {
  int n = blockIdx.x;
  int lane = threadIdx.x;
  const float4* xr = (const float4*)(x + (size_t)n * DD);
  const float4* gr = (const float4*)gw;
  float acc[NE];
#pragma unroll
  for (int e = 0; e < NE; ++e) acc[e] = 0.f;
#pragma unroll
  for (int i = 0; i < 4; ++i) {
    float4 xv = xr[lane + i * 64];
#pragma unroll
    for (int e = 0; e < NE; ++e) {
      float4 gv = gr[e * 256 + lane + i * 64];
      acc[e] += xv.x * gv.x + xv.y * gv.y + xv.z * gv.z + xv.w * gv.w;
    }
  }
#pragma unroll
  for (int e = 0; e < NE; ++e)
#pragma unroll
    for (int off = 32; off > 0; off >>= 1) acc[e] += __shfl_xor(acc[e], off);
  if (lane == 0) {
    float m = acc[0];
#pragma unroll
    for (int e = 1; e < NE; ++e) m = fmaxf(m, acc[e]);
    float p[NE];
    float z = 0.f;
#pragma unroll
    for (int e = 0; e < NE; ++e) { p[e] = expf(acc[e] - m); z += p[e]; }
    float inv = 1.f / z;
    int e1 = 0;
#pragma unroll
    for (int e = 1; e < NE; ++e) if (acc[e] > acc[e1]) e1 = e;
    int e2 = (e1 == 0) ? 1 : 0;
#pragma unroll
    for (int e = 0; e < NE; ++e) if (e != e1 && acc[e] > acc[e2]) e2 = e;
    e_sel[n] = e1;         w_sel[n] = p[e1] * inv;
    e_sel[NTOK + n] = e2;  w_sel[NTOK + n] = p[e2] * inv;
  }
}

// ---------------------------------------------------------------------------
// Build per-expert token lists. Segments padded to multiples of 64 rows so
// m-tiles and row-based swizzles stay aligned. pos order within an expert is
// atomically assigned (order-independent math downstream).
// ---------------------------------------------------------------------------
__global__ __launch_bounds__(256) void kbuild(const int* __restrict__ e_sel,
                                              const float* __restrict__ w_sel,
                                              int* __restrict__ tok,
                                              float* __restrict__ wgt,
                                              int* __restrict__ counts,
                                              int* __restrict__ startp,
                                              int* __restrict__ nmt) {
  __shared__ int sc[NE], scur[NE];
  int t = threadIdx.x;
  if (t < NE) sc[t] = 0;
  __syncthreads();
  for (int s = t; s < NSLOT; s += 256) atomicAdd(&sc[e_sel[s]], 1);
  __syncthreads();
  if (t == 0) {
    int run = 0;
    for (int e = 0; e < NE; ++e) {
      startp[e] = run; scur[e] = run;
      counts[e] = sc[e];
      int nm = (sc[e] + 63) >> 6;
      nmt[e] = nm;
      run += nm << 6;
    }
  }
  __syncthreads();
  for (int s = t; s < NSLOT; s += 256) {
    int e = e_sel[s];
    int pos = atomicAdd(&scur[e], 1);
    tok[pos] = s & (NTOK - 1);
    wgt[pos] = w_sel[s];
  }
}

// ---------------------------------------------------------------------------
// GEMM1+3 fused: h = silu(X@w1) * (X@w3) for one expert m-tile (64 rows) and
// one 128-col slice of H. A staged from f32 x (gather+convert), B from
// pre-transposed pre-swizzled bf16 weights (linear 16B copies into LDS).
// h written bf16, pre-swizzled, to hws [padded_slots][H].
// ---------------------------------------------------------------------------
__global__ __launch_bounds__(256) void kgemm13(
    const float* __restrict__ x, const unsigned short* __restrict__ w1t,
    const unsigned short* __restrict__ w3t, unsigned short* __restrict__ hws,
    const int* __restrict__ tok, const int* __restrict__ counts,
    const int* __restrict__ startp, const int* __restrict__ nmt) {
  __shared__ __align__(16) char smem[40 * 1024];
  char* As = smem;               // 64 x 128B  (8KB)
  char* B1s = smem + 8 * 1024;   // 128 x 128B (16KB)
  char* B3s = smem + 24 * 1024;  // 128 x 128B (16KB)
  int e = blockIdx.z, mt = blockIdx.y;
  if (mt >= nmt[e]) return;
  int nt = blockIdx.x;
  int base = startp[e] + mt * 64;
  int rem = counts[e] - mt * 64;
  int n0 = nt * 128;
  int tid = threadIdx.x, lane = tid & 63, wave = tid >> 6;
  int wm = wave & 1, wn = wave >> 1;
  int arow = tid >> 3, aseg = tid & 7;
  const char* w1b = (const char*)w1t + (size_t)e * HH * DD * 2;
  const char* w3b = (const char*)w3t + (size_t)e * HH * DD * 2;
  f32x4 accg[2][4], accu[2][4];
#pragma unroll
  for (int i = 0; i < 2; ++i)
#pragma unroll
    for (int j = 0; j < 4; ++j) {
      accg[i][j] = (f32x4){0.f, 0.f, 0.f, 0.f};
      accu[i][j] = (f32x4){0.f, 0.f, 0.f, 0.f};
    }
  for (int k0 = 0; k0 < DD; k0 += 64) {
#pragma unroll
    for (int p = 0; p < 2; ++p) {  // A: gather + convert
      int row = p * 32 + arow;
      short8v v = {0, 0, 0, 0, 0, 0, 0, 0};
      if (row < rem) {
        const float* src = x + (size_t)tok[base + row] * DD + k0 + aseg * 8;
        float4 f0 = *(const float4*)src;
        float4 f1 = *(const float4*)(src + 4);
        v[0] = (short)f2bf(f0.x); v[1] = (short)f2bf(f0.y);
        v[2] = (short)f2bf(f0.z); v[3] = (short)f2bf(f0.w);
        v[4] = (short)f2bf(f1.x); v[5] = (short)f2bf(f1.y);
        v[6] = (short)f2bf(f1.z); v[7] = (short)f2bf(f1.w);
      }
      *(short8v*)(As + row * 128 + ((aseg ^ (row & 7)) << 4)) = v;
    }
#pragma unroll
    for (int p = 0; p < 4; ++p) {  // B: linear 16B copies (data pre-swizzled)
      int row = p * 32 + arow;
      size_t gb = (size_t)(n0 + row) * (DD * 2) + k0 * 2 + aseg * 16;
      *(short8v*)(B1s + row * 128 + aseg * 16) = *(const short8v*)(w1b + gb);
      *(short8v*)(B3s + row * 128 + aseg * 16) = *(const short8v*)(w3b + gb);
    }
    __syncthreads();
#pragma unroll
    for (int ks = 0; ks < 2; ++ks) {
      short8v a[2], b1[4], b3[4];
#pragma unroll
      for (int mf = 0; mf < 2; ++mf) {
        int r = wm * 32 + mf * 16 + (lane & 15);
        int g = (ks << 2) | (lane >> 4);
        a[mf] = *(const short8v*)(As + r * 128 + ((g ^ (r & 7)) << 4));
      }
#pragma unroll
      for (int nf = 0; nf < 4; ++nf) {
        int r = wn * 64 + nf * 16 + (lane & 15);
        int g = (ks << 2) | (lane >> 4);
        int off = r * 128 + ((g ^ (r & 7)) << 4);
        b1[nf] = *(const short8v*)(B1s + off);
        b3[nf] = *(const short8v*)(B3s + off);
      }
#pragma unroll
      for (int mf = 0; mf < 2; ++mf)
#pragma unroll
        for (int nf = 0; nf < 4; ++nf) {
          accg[mf][nf] = __builtin_amdgcn_mfma_f32_16x16x32_bf16(
              a[mf], b1[nf], accg[mf][nf], 0, 0, 0);
          accu[mf][nf] = __builtin_amdgcn_mfma_f32_16x16x32_bf16(
              a[mf], b3[nf], accu[mf][nf], 0, 0, 0);
        }
    }
    __syncthreads();
  }
  // Epilogue: silu(g)*u -> bf16 via LDS restage -> coalesced swizzled store.
  unsigned short* hl = (unsigned short*)smem;  // 64 x 128 bf16 (16KB)
#pragma unroll
  for (int mf = 0; mf < 2; ++mf)
#pragma unroll
    for (int nf = 0; nf < 4; ++nf)
#pragma unroll
      for (int r = 0; r < 4; ++r) {
        int row = wm * 32 + mf * 16 + (lane >> 4) * 4 + r;
        int col = wn * 64 + nf * 16 + (lane & 15);
        float g = accg[mf][nf][r], u = accu[mf][nf][r];
        float h = (g / (1.f + __expf(-g))) * u;
        hl[row * 128 + col] = f2bf(h);
      }
  __syncthreads();
#pragma unroll
  for (int p = 0; p < 4; ++p) {
    int idx = p * 256 + tid;
    int row = idx >> 4, g = idx & 15;
    int dp = base + row;
    size_t db = (size_t)dp * (HH * 2) + (size_t)n0 * 2 +
                (((g & 8) | ((g & 7) ^ (dp & 7))) << 4);
    *(short8v*)((char*)hws + db) =
        *(const short8v*)((const char*)hl + row * 256 + (g << 4));
  }
}

// ---------------------------------------------------------------------------
// GEMM2: y = h @ w2, scaled by routing weight, scattered into out via
// atomicAdd (exactly 2 commutative adds per element -> deterministic).
// ---------------------------------------------------------------------------
__global__ __launch_bounds__(256) void kgemm2(
    const unsigned short* __restrict__ hws, const unsigned short* __restrict__ w2t,
    float* __restrict__ out, const int* __restrict__ tok,
    const float* __restrict__ wgt, const int* __restrict__ counts,
    const int* __restrict__ startp, const int* __restrict__ nmt) {
  __shared__ __align__(16) char smem[24 * 1024];
  char* As = smem;              // 64 x 128B (8KB)
  char* Bs = smem + 8 * 1024;   // 128 x 128B (16KB)
  int e = blockIdx.z, mt = blockIdx.y;
  if (mt >= nmt[e]) return;
  int nt = blockIdx.x;  // over D
  int base = startp[e] + mt * 64;
  int rem = counts[e] - mt * 64;
  int n0 = nt * 128;
  int tid = threadIdx.x, lane = tid & 63, wave = tid >> 6;
  int wm = wave & 1, wn = wave >> 1;
  int arow = tid >> 3, aseg = tid & 7;
  const char* w2b = (const char*)w2t + (size_t)e * DD * HH * 2;
  const char* hb = (const char*)hws;
  f32x4 acc[2][4];
#pragma unroll
  for (int i = 0; i < 2; ++i)
#pragma unroll
    for (int j = 0; j < 4; ++j) acc[i][j] = (f32x4){0.f, 0.f, 0.f, 0.f};
  for (int k0 = 0; k0 < HH; k0 += 64) {
#pragma unroll
    for (int p = 0; p < 2; ++p) {
      int row = p * 32 + arow;
      size_t gb = (size_t)(base + row) * (HH * 2) + k0 * 2 + aseg * 16;
      *(short8v*)(As + row * 128 + aseg * 16) = *(const short8v*)(hb + gb);
    }
#pragma unroll
    for (int p = 0; p < 4; ++p) {
      int row = p * 32 + arow;
      size_t gb = (size_t)(n0 + row) * (HH * 2) + k0 * 2 + aseg * 16;
      *(short8v*)(Bs + row * 128 + aseg * 16) = *(const short8v*)(w2b + gb);
    }
    __syncthreads();
#pragma unroll
    for (int ks = 0; ks < 2; ++ks) {
      short8v a[2], b[4];
#pragma unroll
      for (int mf = 0; mf < 2; ++mf) {
        int r = wm * 32 + mf * 16 + (lane & 15);
        int g = (ks << 2) | (lane >> 4);
        a[mf] = *(const short8v*)(As + r * 128 + ((g ^ (r & 7)) << 4));
      }
#pragma unroll
      for (int nf = 0; nf < 4; ++nf) {
        int r = wn * 64 + nf * 16 + (lane & 15);
        int g = (ks << 2) | (lane >> 4);
        b[nf] = *(const short8v*)(Bs + r * 128 + ((g ^ (r & 7)) << 4));
      }
#pragma unroll
      for (int mf = 0; mf < 2; ++mf)
#pragma unroll
        for (int nf = 0; nf < 4; ++nf)
          acc[mf][nf] = __builtin_amdgcn_mfma_f32_16x16x32_bf16(
              a[mf], b[nf], acc[mf][nf], 0, 0, 0);
    }
    __syncthreads();
  }
#pragma unroll
  for (int mf = 0; mf < 2; ++mf)
#pragma unroll
    for (int r = 0; r < 4; ++r) {
      int row = wm * 32 + mf * 16 + (lane >> 4) * 4 + r;
      if (row < rem) {
        int t = tok[base + row];
        float w = wgt[base + row];
        float* orow = out + (size_t)t * DD + n0;
#pragma unroll
        for (int nf = 0; nf < 4; ++nf) {
          int col = wn * 64 + nf * 16 + (lane & 15);
          atomicAdd(orow + col, w * acc[mf][nf][r]);
        }
      }
    }
}

// ---------------------------------------------------------------------------
extern "C" void kernel_launch(void* const* d_in, const int* in_sizes, int n_in,
                              void* d_out, int out_size, void* d_ws, size_t ws_size,
                              hipStream_t stream) {
  const float* x  = (const float*)d_in[0];
  const float* gw = (const float*)d_in[1];
  const float* w1 = (const float*)d_in[2];
  const float* w2 = (const float*)d_in[3];
  const float* w3 = (const float*)d_in[4];
  float* out = (float*)d_out;
  char* ws = (char*)d_ws;
  const size_t MB = 1024 * 1024;
  if (ws_size < 76 * MB) return;  // avoid OOB scratch writes

  unsigned short* W1t = (unsigned short*)(ws);            // 32MB
  unsigned short* W3t = (unsigned short*)(ws + 32 * MB);  // 32MB
  unsigned short* W2t = (unsigned short*)(ws);            // reuse after gemm13
  unsigned short* hws = (unsigned short*)(ws + 64 * MB);  // 2560*2048 bf16 = 10.5MB
  char* meta = ws + 75 * MB;
  int*   e_sel  = (int*)meta;                       // 2048
  float* w_sel  = (float*)(meta + 8192);            // 2048
  int*   tok    = (int*)(meta + 16384);             // 2560
  float* wgt    = (float*)(meta + 16384 + 10240);   // 2560
  int*   counts = (int*)(meta + 16384 + 20480);     // 8
  int*   startp = counts + 8;
  int*   nmt    = counts + 16;

  hipMemsetAsync(out, 0, (size_t)out_size * sizeof(float), stream);
  ktranspose<<<dim3(32, 16, 8), 256, 0, stream>>>(w1, W1t, DD, HH);
  ktranspose<<<dim3(32, 16, 8), 256, 0, stream>>>(w3, W3t, DD, HH);
  krouter<<<dim3(NTOK), 64, 0, stream>>>(x, gw, e_sel, w_sel);
  kbuild<<<1, 256, 0, stream>>>(e_sel, w_sel, tok, wgt, counts, startp, nmt);
  kgemm13<<<dim3(16, 32, 8), 256, 0, stream>>>(x, W1t, W3t, hws, tok, counts,
                                               startp, nmt);
  ktranspose<<<dim3(16, 32, 8), 256, 0, stream>>>(w2, W2t, HH, DD);
  kgemm2<<<dim3(8, 32, 8), 256, 0, stream>>>(hws, W2t, out, tok, wgt, counts,
                                             startp, nmt);
}